// Round 10
// baseline (1426.054 us; speedup 1.0000x reference)
//
#include <hip/hip_runtime.h>

#define NQc 100000
#define NSc 2000
#define Dc 128
#define DCc 64
#define HTc 128
#define Bc 128
#define Tc 500
#define BTc (Bc*Tc)
#define NNZ_HGc 300000
#define NNZ_GCNc 64000
#define NNZ_SIMc 1000000
#define LINc 320
#define G4c 512

using bf16x8  = __attribute__((ext_vector_type(8))) short;
using floatx4 = __attribute__((ext_vector_type(4))) float;
typedef _Float16 half2v __attribute__((ext_vector_type(2)));

__device__ __forceinline__ float sigf(float x){ return 1.0f/(1.0f + __expf(-x)); }
__device__ __forceinline__ float tanhfast(float x){ return 2.0f*sigf(2.0f*x) - 1.0f; }

__device__ __forceinline__ unsigned short bf16r(float x){
  unsigned u = __float_as_uint(x);
  unsigned r = (u + 0x7FFFu + ((u>>16)&1u)) >> 16;
  return (unsigned short)r;
}
__device__ __forceinline__ unsigned pack2(float2 v){
  return (unsigned)bf16r(v.x) | ((unsigned)bf16r(v.y) << 16);
}
__device__ __forceinline__ float bflo(unsigned u){ return __uint_as_float(u << 16); }
__device__ __forceinline__ float bfhi(unsigned u){ return __uint_as_float(u & 0xFFFF0000u); }

__device__ __forceinline__ float wredsum(float v){
  #pragma unroll
  for (int off=32; off>0; off>>=1) v += __shfl_xor(v, off, 64);
  return v;
}

__global__ void fill_kernel(float* p, float v, int n){
  int i = blockIdx.x*blockDim.x + threadIdx.x;
  if (i<n) p[i] = v;
}

// ---------------- converts ----------------
__global__ void cvt_bf16_kernel(const float* __restrict__ in, unsigned short* __restrict__ out, long n){
  long i = (long)blockIdx.x*blockDim.x + threadIdx.x;
  long stride = (long)gridDim.x*blockDim.x;
  for (; i<n; i+=stride) out[i] = bf16r(in[i]);
}

// fused small weight converts
__global__ void cvt_weights_kernel(
    const float* __restrict__ w_ih, unsigned short* __restrict__ w_ih_bf,
    const float* __restrict__ fc1_w, unsigned short* __restrict__ fc1_wT,
    const float* __restrict__ w_g3, unsigned short* __restrict__ w_g3T,
    const float* __restrict__ w_hh, _Float16* __restrict__ w_hh_h,
    const float* __restrict__ b_ih, const float* __restrict__ b_hh, float* __restrict__ biasP)
{
  int i = blockIdx.x*blockDim.x + threadIdx.x;
  const int T0 = G4c*LINc;            // 163840
  const int T1 = T0 + 384*HTc;        // +49152
  const int T2 = T1 + Dc*Dc;          // +16384
  const int T3 = T2 + G4c*HTc;        // +65536
  const int T4 = T3 + G4c;            // +512
  if (i < T0){
    int r = i/LINc, c = i%LINc;
    int rp = (r&127)*4 + (r>>7);
    w_ih_bf[(size_t)rp*LINc + c] = bf16r(w_ih[i]);
  } else if (i < T1){
    int j = i - T0; int r = j/HTc, c = j%HTc;
    fc1_wT[(size_t)c*384 + r] = bf16r(fc1_w[j]);
  } else if (i < T2){
    int j = i - T1; int r = j/Dc, c = j%Dc;
    w_g3T[(size_t)c*Dc + r] = bf16r(w_g3[j]);
  } else if (i < T3){
    int j = i - T2;
    w_hh_h[j] = (_Float16)w_hh[j];
  } else if (i < T4){
    int j = i - T3;
    biasP[(j&127)*4 + (j>>7)] = b_ih[j] + b_hh[j];
  }
}

// ---------------- CSR build (fused) ----------------
__global__ void hist_all_kernel(const int* __restrict__ sim_src, int* cnt_sim,
                                const int* __restrict__ hg_q, int* cnt_hgq,
                                const int* __restrict__ hg_c, int* cnt_hgc,
                                const int* __restrict__ gcn_dst, int* cnt_gcn){
  long i = (long)blockIdx.x*blockDim.x + threadIdx.x;
  long stride = (long)gridDim.x*blockDim.x;
  const long T0=NNZ_SIMc, T1=T0+NNZ_HGc, T2=T1+NNZ_HGc, T3=T2+NNZ_GCNc;
  for (; i<T3; i+=stride){
    if (i<T0)      atomicAdd(&cnt_sim[sim_src[i]], 1);
    else if (i<T1) atomicAdd(&cnt_hgq[hg_q[i-T0]], 1);
    else if (i<T2) atomicAdd(&cnt_hgc[hg_c[i-T1]], 1);
    else           atomicAdd(&cnt_gcn[gcn_dst[i-T2]], 1);
  }
}

#define BS_STRIDE 104
__global__ __launch_bounds__(1024) void scan_local_all_kernel(
    const int* __restrict__ cnt_sim, int* rp_sim,
    const int* __restrict__ cnt_hgq, int* rp_hgq,
    const int* __restrict__ cnt_hgc, int* rp_hgc,
    const int* __restrict__ cnt_gcn, int* rp_gcn,
    int* __restrict__ bsum, float* __restrict__ dinv)
{
  __shared__ int buf[1024];
  int b = blockIdx.x, tid = threadIdx.x;
  const int* cnt; int* rp; int* bs; int n; int lb; int seg;
  if (b < 98)      { seg=0; cnt=cnt_sim; rp=rp_sim; n=NQc; lb=b; }
  else if (b <196) { seg=1; cnt=cnt_hgq; rp=rp_hgq; n=NQc; lb=b-98; }
  else if (b <198) { seg=2; cnt=cnt_hgc; rp=rp_hgc; n=NSc; lb=b-196; }
  else             { seg=3; cnt=cnt_gcn; rp=rp_gcn; n=NSc; lb=b-198; }
  bs = bsum + seg*BS_STRIDE;
  int i = lb*1024 + tid;
  int v = (i<n) ? cnt[i] : 0;
  if (seg==3 && i<n) dinv[i] = rsqrtf((float)v + 1.0f);
  buf[tid] = v;
  __syncthreads();
  for (int off=1; off<1024; off<<=1){
    int t = (tid>=off) ? buf[tid-off] : 0;
    __syncthreads();
    buf[tid] += t;
    __syncthreads();
  }
  if (i<n) rp[i] = buf[tid] - v;
  if (tid==1023) bs[lb] = buf[1023];
}
__global__ __launch_bounds__(128) void scan_bsum_all_kernel(int* bsum){
  __shared__ int s[128];
  int seg = blockIdx.x, tid = threadIdx.x;
  int nb = (seg<2) ? 98 : 2;
  int* bs = bsum + seg*BS_STRIDE;
  int v = (tid<nb) ? bs[tid] : 0;
  s[tid] = v;
  __syncthreads();
  for (int off=1; off<128; off<<=1){
    int t = (tid>=off) ? s[tid-off] : 0;
    __syncthreads();
    s[tid] += t;
    __syncthreads();
  }
  if (tid<nb) bs[tid] = s[tid] - v;
  if (tid==0) bs[nb] = s[127];
}
__global__ void scan_add_all_kernel(
    int* rp_sim, int* cnt_sim, int* rp_hgq, int* cnt_hgq,
    int* rp_hgc, int* cnt_hgc, int* rp_gcn, int* cnt_gcn,
    const int* __restrict__ bsum)
{
  int b = blockIdx.x, tid = threadIdx.x;
  int* rp; int* cur; const int* bs; int n; int lb; int nb;
  if (b < 391)      { rp=rp_sim; cur=cnt_sim; bs=bsum;               n=NQc; lb=b;     nb=98; }
  else if (b < 782) { rp=rp_hgq; cur=cnt_hgq; bs=bsum+BS_STRIDE;     n=NQc; lb=b-391; nb=98; }
  else if (b < 790) { rp=rp_hgc; cur=cnt_hgc; bs=bsum+2*BS_STRIDE;   n=NSc; lb=b-782; nb=2; }
  else              { rp=rp_gcn; cur=cnt_gcn; bs=bsum+3*BS_STRIDE;   n=NSc; lb=b-790; nb=2; }
  int i = lb*256 + tid;
  if (i<n){ int r = rp[i] + bs[i>>10]; rp[i]=r; cur[i]=r; }
  if (lb==0 && tid==0) rp[n] = bs[nb];
}

__global__ void scatter_all_kernel(
    const int* __restrict__ sim_src, const int* __restrict__ sim_dst, const float* __restrict__ sim_vals,
    int* cur_sim, int* col_sim, float* val_sim,
    const int* __restrict__ hg_q, const int* __restrict__ hg_c,
    const float* __restrict__ hg_vals_qc, const float* __restrict__ hg_vals_cq,
    int* cur_hgq, int* col_hgq, float* val_hgq,
    int* cur_hgc, int* col_hgc, float* val_hgc,
    const int* __restrict__ gcn_dst, const int* __restrict__ gcn_src,
    int* cur_gcn, int* src_gcn)
{
  long i = (long)blockIdx.x*blockDim.x + threadIdx.x;
  long stride = (long)gridDim.x*blockDim.x;
  const long T0=NNZ_SIMc, T1=T0+NNZ_HGc, T2=T1+NNZ_HGc, T3=T2+NNZ_GCNc;
  for (; i<T3; i+=stride){
    if (i<T0){
      int r = sim_src[i]; int p = atomicAdd(&cur_sim[r],1);
      col_sim[p] = sim_dst[i]; val_sim[p] = sim_vals[i];
    } else if (i<T1){
      long j=i-T0; int r = hg_q[j]; int p = atomicAdd(&cur_hgq[r],1);
      col_hgq[p] = hg_c[j]; val_hgq[p] = hg_vals_qc[j];
    } else if (i<T2){
      long j=i-T1; int r = hg_c[j]; int p = atomicAdd(&cur_hgc[r],1);
      col_hgc[p] = hg_q[j]; val_hgc[p] = hg_vals_cq[j];
    } else {
      long j=i-T2; int r = gcn_dst[j]; int p = atomicAdd(&cur_gcn[r],1);
      src_gcn[p] = gcn_src[j];
    }
  }
}

// ---------------- fp32 GEMM (small NS-sized matmuls) ----------------
#define BM 64
#define BN 64
#define BK 16
__global__ __launch_bounds__(256) void gemm_kernel(
    const float* __restrict__ A, int lda,
    const float* __restrict__ Bm, float* __restrict__ C,
    unsigned short* __restrict__ Cbf, float* __restrict__ Ccopy,
    const float* __restrict__ bias, const float* __restrict__ gsrc,
    int M, int N, int K, int ep)
{
  __shared__ float As[BM][BK+4];
  __shared__ float Bs[BK][BN+4];
  int tid = threadIdx.x;
  int tx = tid & 15, ty = tid >> 4;
  int mBase = blockIdx.y*BM, nBase = blockIdx.x*BN;
  float acc[4][4];
  #pragma unroll
  for (int i=0;i<4;i++)
    #pragma unroll
    for (int j=0;j<4;j++) acc[i][j]=0.f;
  int arow = tid>>2, ac4 = tid&3;
  for (int kt=0; kt<K; kt+=BK){
    {
      int m = mBase + arow;
      float4 v = make_float4(0.f,0.f,0.f,0.f);
      if (m < M) v = *(const float4*)(A + (size_t)m*lda + kt + ac4*4);
      *(float4*)&As[arow][ac4*4] = v;
    }
    {
      int kr = tid>>4, c4 = tid&15;
      float4 v = *(const float4*)(Bm + (size_t)(kt+kr)*N + nBase + c4*4);
      *(float4*)&Bs[kr][c4*4] = v;
    }
    __syncthreads();
    #pragma unroll
    for (int k=0;k<BK;k++){
      float a0=As[ty*4+0][k],a1=As[ty*4+1][k],a2=As[ty*4+2][k],a3=As[ty*4+3][k];
      float b0=Bs[k][tx*4+0],b1=Bs[k][tx*4+1],b2=Bs[k][tx*4+2],b3=Bs[k][tx*4+3];
      acc[0][0]+=a0*b0; acc[0][1]+=a0*b1; acc[0][2]+=a0*b2; acc[0][3]+=a0*b3;
      acc[1][0]+=a1*b0; acc[1][1]+=a1*b1; acc[1][2]+=a1*b2; acc[1][3]+=a1*b3;
      acc[2][0]+=a2*b0; acc[2][1]+=a2*b1; acc[2][2]+=a2*b2; acc[2][3]+=a2*b3;
      acc[3][0]+=a3*b0; acc[3][1]+=a3*b1; acc[3][2]+=a3*b2; acc[3][3]+=a3*b3;
    }
    __syncthreads();
  }
  #pragma unroll
  for (int i=0;i<4;i++){
    int m = mBase + ty*4 + i;
    if (m >= M) continue;
    #pragma unroll
    for (int j=0;j<4;j++){
      int n = nBase + tx*4 + j;
      float v = acc[i][j];
      if (bias)  v += bias[n];
      if (ep==1)      v = gsrc[(size_t)m*N + n] * sigf(v);
      C[(size_t)m*N + n] = v;
      if (Cbf)   Cbf[(size_t)m*N + n] = bf16r(v);
      if (Ccopy) Ccopy[(size_t)m*N + n] = v;
    }
  }
}

// ---------------- MFMA bf16 GEMM ----------------
// ep: 0 = +bias(+bias2); 1 = gsrc*sigmoid(acc+bias); 2 = relu(acc+bias);
// ep 3 = fused head: out[row] = sig( relu(acc+bias)·fc2w + fc2b ), no C store.
__global__ __launch_bounds__(256) void mfma_gemm_kernel(
    const unsigned short* __restrict__ A1, int lda1,
    const unsigned short* __restrict__ A2, int lda2, int ksplit,
    const unsigned short* __restrict__ Bt,
    float* __restrict__ C, unsigned short* __restrict__ Cbf,
    const float* __restrict__ bias, const float* __restrict__ bias2,
    const float* __restrict__ gsrc,
    const float* __restrict__ fc2w, const float* __restrict__ fc2b, float* __restrict__ outp,
    int M, int N, int K, int ep)
{
  __shared__ unsigned short Asm[128*64];
  __shared__ unsigned short Bsm[128*64];
  __shared__ float rps[2][128];
  int tid = threadIdx.x;
  int wave = tid>>6, lane = tid&63;
  int quad = lane>>4, l16 = lane&15;
  int m0 = blockIdx.y*128, n0 = blockIdx.x*128;
  int wm = (wave&1)*64, wn = (wave>>1)*64;
  floatx4 acc[4][4];
  #pragma unroll
  for (int i=0;i<4;i++)
    #pragma unroll
    for (int j=0;j<4;j++) acc[i][j] = (floatx4){0.f,0.f,0.f,0.f};

  for (int kt=0; kt<K; kt+=64){
    #pragma unroll
    for (int i=0;i<4;i++){
      int idx = i*256 + tid;
      int row = idx>>3, blk = idx&7;
      int kcol = kt + blk*8;
      {
        const unsigned short* src = (kcol < ksplit)
            ? (A1 + (size_t)(m0+row)*lda1 + kcol)
            : (A2 + (size_t)(m0+row)*lda2 + (kcol - ksplit));
        float4 v = *(const float4*)src;
        *(float4*)&Asm[row*64 + ((blk ^ (row&7))<<3)] = v;
      }
      {
        const unsigned short* src = Bt + (size_t)(n0+row)*K + kcol;
        float4 v = *(const float4*)src;
        *(float4*)&Bsm[row*64 + ((blk ^ (row&7))<<3)] = v;
      }
    }
    __syncthreads();
    #pragma unroll
    for (int ks=0; ks<2; ks++){
      bf16x8 af[4], bfr[4];
      #pragma unroll
      for (int mt=0;mt<4;mt++){
        int row = wm + mt*16 + l16;
        int blk = ks*4 + quad;
        af[mt] = *(const bf16x8*)&Asm[row*64 + ((blk ^ (row&7))<<3)];
      }
      #pragma unroll
      for (int nt=0;nt<4;nt++){
        int row = wn + nt*16 + l16;
        int blk = ks*4 + quad;
        bfr[nt] = *(const bf16x8*)&Bsm[row*64 + ((blk ^ (row&7))<<3)];
      }
      #pragma unroll
      for (int mt=0;mt<4;mt++)
        #pragma unroll
        for (int nt=0;nt<4;nt++)
          acc[mt][nt] = __builtin_amdgcn_mfma_f32_16x16x32_bf16(af[mt], bfr[nt], acc[mt][nt], 0,0,0);
    }
    __syncthreads();
  }
  if (ep == 3){
    float fw[4], fb[4];
    #pragma unroll
    for (int nt=0;nt<4;nt++){ int col = wn + nt*16 + l16; fw[nt] = fc2w[col]; fb[nt] = bias[col]; }
    #pragma unroll
    for (int mt=0;mt<4;mt++){
      #pragma unroll
      for (int r=0;r<4;r++){
        float s = 0.f;
        #pragma unroll
        for (int nt=0;nt<4;nt++){
          float v = acc[mt][nt][r] + fb[nt];
          v = fmaxf(v, 0.f);
          s += v*fw[nt];
        }
        s += __shfl_xor(s,1); s += __shfl_xor(s,2); s += __shfl_xor(s,4); s += __shfl_xor(s,8);
        if (l16 == 0) rps[wave>>1][wm + mt*16 + quad*4 + r] = s;
      }
    }
    __syncthreads();
    if (tid < 128){
      int row = m0 + tid;
      if (row < M) outp[row] = sigf(rps[0][tid] + rps[1][tid] + fc2b[0]);
    }
    return;
  }
  #pragma unroll
  for (int mt=0;mt<4;mt++){
    #pragma unroll
    for (int nt=0;nt<4;nt++){
      int col = n0 + wn + nt*16 + l16;
      #pragma unroll
      for (int r=0;r<4;r++){
        int row = m0 + wm + mt*16 + quad*4 + r;
        if (row < M){
          float v = acc[mt][nt][r];
          if (bias)  v += bias[col];
          if (bias2) v += bias2[col];
          if (ep==1)      v = gsrc[(size_t)row*N + col] * sigf(v);
          else if (ep==2) v = fmaxf(v, 0.f);
          C[(size_t)row*N + col] = v;
          if (Cbf) Cbf[(size_t)row*N + col] = bf16r(v);
        }
      }
    }
  }
}

// ---------------- SpMM (CSR, wave/row, D=128, bf16 gathers, unroll-4) ----------------
__global__ __launch_bounds__(256) void spmm_bf_kernel(
    const int* __restrict__ rowptr, const int* __restrict__ col, const float* __restrict__ val,
    const unsigned short* __restrict__ xbf, const float* __restrict__ resid,
    const float* __restrict__ resid2, float beta,
    float* __restrict__ y, unsigned short* __restrict__ ybf,
    float* __restrict__ sumbuf, unsigned short* __restrict__ sumbf,
    float alpha, int nrows)
{
  int w = (int)((blockIdx.x*(unsigned)blockDim.x + threadIdx.x) >> 6);
  int lane = threadIdx.x & 63;
  if (w >= nrows) return;
  int beg = rowptr[w], end = rowptr[w+1];
  const unsigned* x2 = (const unsigned*)xbf;
  float ax=0.f, ay=0.f;
  int k = beg;
  for (; k+4 <= end; k+=4){
    int c0=col[k], c1=col[k+1], c2=col[k+2], c3=col[k+3];
    float v0=val[k], v1=val[k+1], v2=val[k+2], v3=val[k+3];
    unsigned u0 = x2[(size_t)c0*64 + lane];
    unsigned u1 = x2[(size_t)c1*64 + lane];
    unsigned u2 = x2[(size_t)c2*64 + lane];
    unsigned u3 = x2[(size_t)c3*64 + lane];
    ax += v0*bflo(u0); ay += v0*bfhi(u0);
    ax += v1*bflo(u1); ay += v1*bfhi(u1);
    ax += v2*bflo(u2); ay += v2*bfhi(u2);
    ax += v3*bflo(u3); ay += v3*bfhi(u3);
  }
  for (; k<end; k++){
    int c = col[k]; float v = val[k];
    unsigned u = x2[(size_t)c*64 + lane];
    ax += v*bflo(u); ay += v*bfhi(u);
  }
  ax*=alpha; ay*=alpha;
  if (resid){ float2 r = ((const float2*)resid)[(size_t)w*64+lane]; ax+=r.x; ay+=r.y; }
  if (resid2){ float2 r = ((const float2*)resid2)[(size_t)w*64+lane]; ax+=beta*r.x; ay+=beta*r.y; }
  float2 o; o.x=ax; o.y=ay;
  ((float2*)y)[(size_t)w*64+lane] = o;
  if (ybf) ((unsigned*)ybf)[(size_t)w*64+lane] = pack2(o);
  if (sumbuf){
    float2 s = ((float2*)sumbuf)[(size_t)w*64+lane];
    s.x+=ax; s.y+=ay;
    ((float2*)sumbuf)[(size_t)w*64+lane] = s;
    if (sumbf) ((unsigned*)sumbf)[(size_t)w*64+lane] = pack2(s);
  }
}

__global__ __launch_bounds__(256) void gcn_spmm_kernel(
    const int* __restrict__ rowptr, const int* __restrict__ src, const float* __restrict__ dinv,
    const float* __restrict__ h, const float* __restrict__ bias, float* __restrict__ out, int nrows)
{
  int w = (int)((blockIdx.x*(unsigned)blockDim.x + threadIdx.x) >> 6);
  int lane = threadIdx.x & 63;
  if (w >= nrows) return;
  int beg = rowptr[w], end = rowptr[w+1];
  const float2* h2 = (const float2*)h;
  float dr = dinv[w];
  float2 self = h2[(size_t)w*64+lane];
  float ax = dr*self.x, ay = dr*self.y;
  int k = beg;
  for (; k+4 <= end; k+=4){
    int s0=src[k], s1=src[k+1], s2=src[k+2], s3=src[k+3];
    float d0=dinv[s0], d1=dinv[s1], d2=dinv[s2], d3=dinv[s3];
    float2 h0=h2[(size_t)s0*64+lane], h1v=h2[(size_t)s1*64+lane];
    float2 h2v=h2[(size_t)s2*64+lane], h3=h2[(size_t)s3*64+lane];
    ax += d0*h0.x + d1*h1v.x + d2*h2v.x + d3*h3.x;
    ay += d0*h0.y + d1*h1v.y + d2*h2v.y + d3*h3.y;
  }
  for (; k<end; k++){
    int s = src[k]; float ds = dinv[s];
    float2 hv = h2[(size_t)s*64+lane];
    ax += ds*hv.x; ay += ds*hv.y;
  }
  ax*=dr; ay*=dr;
  float2 b2 = ((const float2*)bias)[lane];
  float2 o; o.x = fmaxf(ax + b2.x, 0.f); o.y = fmaxf(ay + b2.y, 0.f);
  ((float2*)out)[(size_t)w*64+lane] = o;
}

// ---------------- gather + gated fusion -> lstm_in_bf [BT,320] bf16 ----------------
__global__ __launch_bounds__(256) void gather_fuse_kernel(
    const int* __restrict__ q_seq, const int* __restrict__ s_seq, const int* __restrict__ a_seq,
    const float* __restrict__ skill_sum, const float* __restrict__ one_q,
    const float* __restrict__ two_skill, const float* __restrict__ three_sum,
    const float* __restrict__ s_emb, const float* __restrict__ q_emb, const float* __restrict__ c_emb,
    const float* __restrict__ w_sg1, const float* __restrict__ w_sg2,
    const float* __restrict__ w_qg1, const float* __restrict__ w_qg3,
    const float* __restrict__ b_sg1, const float* __restrict__ b_sg2,
    const float* __restrict__ b_qg1, const float* __restrict__ b_qg3,
    unsigned short* __restrict__ lstm_in_bf)
{
  int idx = (int)((blockIdx.x*(unsigned)blockDim.x + threadIdx.x) >> 6);
  int lane = threadIdx.x & 63;
  if (idx >= BTc) return;
  int q = q_seq[idx], s = s_seq[idx], a = a_seq[idx];
  float2 obs, tbs, obq, tbq;
  if (s < NSc){
    obs = ((const float2*)(skill_sum + (size_t)s*Dc))[lane];
    obs.x *= (1.f/3.f); obs.y *= (1.f/3.f);
    tbs = ((const float2*)(two_skill + (size_t)s*Dc))[lane];
  } else {
    obs = ((const float2*)(s_emb + (size_t)NSc*Dc))[lane];
    tbs = obs;
  }
  if (q < NQc){
    obq = ((const float2*)(one_q + (size_t)q*Dc))[lane];
    tbq = ((const float2*)(three_sum + (size_t)q*Dc))[lane];
    tbq.x *= (1.f/3.f); tbq.y *= (1.f/3.f);
  } else {
    obq = ((const float2*)(q_emb + (size_t)NQc*Dc))[lane];
    tbq = obq;
  }
  float2 w1 = ((const float2*)w_sg1)[lane];
  float2 w2 = ((const float2*)w_sg2)[lane];
  float2 w3 = ((const float2*)w_qg1)[lane];
  float2 w4 = ((const float2*)w_qg3)[lane];
  float p1 = wredsum(obs.x*w1.x + obs.y*w1.y);
  float p2 = wredsum(tbs.x*w2.x + tbs.y*w2.y);
  float p3 = wredsum(obq.x*w3.x + obq.y*w3.y);
  float p4 = wredsum(tbq.x*w4.x + tbq.y*w4.y);
  float g1 = sigf(p1 + b_sg1[0]);
  float g2 = sigf(p2 + b_sg2[0]);
  float g3 = sigf(p3 + b_qg1[0]);
  float g4 = sigf(p4 + b_qg3[0]);
  float2 fs, fq;
  fs.x = g1*obs.x + g2*tbs.x; fs.y = g1*obs.y + g2*tbs.y;
  fq.x = g3*obq.x + g4*tbq.x; fq.y = g3*obq.y + g4*tbq.y;
  unsigned* rowb = (unsigned*)(lstm_in_bf + (size_t)idx*LINc);
  rowb[lane]      = pack2(fq);
  rowb[64 + lane] = pack2(fs);
  if (lane < 32){
    float2 cv = ((const float2*)(c_emb + (size_t)a*DCc))[lane];
    rowb[128 + lane] = pack2(cv);
  }
}

// ---------------- LSTM v7: chunked staging — NO HBM ops in the step loop ----------------
// 512 thr: j=tid>>2, sub=tid&3. Gates i,f LDS-resident; g,o streamed from L2 (hot, fixed addr).
// T processed in 25 chunks of 20: x bulk-loaded into LDS per chunk; h staged in LDS, flushed per chunk.
#define H2(u) __builtin_bit_cast(half2v, u)
#define CH 20
__global__ __launch_bounds__(512, 2) void lstm_kernel(
    const float* __restrict__ xpart, const _Float16* __restrict__ w_hh_h,
    unsigned short* __restrict__ hs_bf)
{
  __shared__ __align__(16) unsigned short wlds[32768];     // 64 KB gates i,f
  __shared__ __align__(16) float x_lds[CH*512];            // 40 KB
  __shared__ __align__(16) _Float16 h_lds[2][HTc];
  __shared__ __align__(16) unsigned short h_stage[CH*HTc]; // 5 KB
  int b = blockIdx.x, tid = threadIdx.x;
  int j = tid >> 2, sub = tid & 3;
  {
    const uint4* wsrc = (const uint4*)w_hh_h;
    uint4* wdst = (uint4*)wlds;
    #pragma unroll
    for (int i=0;i<8;i++){
      int g = i >> 2, q = i & 3;
      int srcIdx = ((g*128 + j)*128 + sub*32 + q*8) >> 3;
      wdst[i*512 + tid] = wsrc[srcIdx];
    }
  }
  const uint4* wp2 = (const uint4*)(w_hh_h + (size_t)(2*128 + j)*HTc + sub*32);
  const uint4* wp3 = (const uint4*)(w_hh_h + (size_t)(3*128 + j)*HTc + sub*32);
  if (tid < HTc) h_lds[0][tid] = (_Float16)0.f;
  float c = 0.f;
  const float* xp = xpart + (size_t)b*Tc*G4c;
  unsigned short* hb = hs_bf + (size_t)b*Tc*HTc;
  __syncthreads();
  for (int ch=0; ch<Tc/CH; ch++){
    // flush previous chunk's h_stage to global (coalesced dword stores)
    if (ch > 0){
      const unsigned* st = (const unsigned*)h_stage;
      unsigned* dst = (unsigned*)hb + (ch-1)*(CH*HTc/2);
      #pragma unroll
      for (int i=0;i<CH*HTc/2/512;i++) dst[i*512+tid] = st[i*512+tid];
      if (tid < (CH*HTc/2)%512) dst[(CH*HTc/2/512)*512+tid] = st[(CH*HTc/2/512)*512+tid];
    }
    // bulk-load x chunk into LDS (one drain per chunk)
    {
      int t0 = ch*CH;
      #pragma unroll
      for (int k2=0;k2<CH;k2++)
        x_lds[k2*512 + tid] = xp[(size_t)(t0+k2)*G4c + tid];
    }
    __syncthreads();
    const uint4* wl = (const uint4*)wlds;
    for (int t=0; t<CH; t++){
      int cur = t & 1;   // CH even -> parity consistent across chunks
      float xcur = x_lds[t*512 + tid];
      uint4 w2q[4], w3q[4];
      #pragma unroll
      for (int q=0;q<4;q++){ w2q[q] = wp2[q]; w3q[q] = wp3[q]; }
      const uint4* hsrc = (const uint4*)&h_lds[cur][sub*32];
      uint4 hq[4];
      #pragma unroll
      for (int q=0;q<4;q++) hq[q] = hsrc[q];
      float p0=0.f,p1=0.f,p2=0.f,p3=0.f;
      #pragma unroll
      for (int q=0;q<4;q++){
        uint4 w0 = wl[(0*4+q)*512 + tid];
        uint4 w1 = wl[(1*4+q)*512 + tid];
#if __has_builtin(__builtin_amdgcn_fdot2)
        p0 = __builtin_amdgcn_fdot2(H2(w0.x), H2(hq[q].x), p0, false);
        p0 = __builtin_amdgcn_fdot2(H2(w0.y), H2(hq[q].y), p0, false);
        p0 = __builtin_amdgcn_fdot2(H2(w0.z), H2(hq[q].z), p0, false);
        p0 = __builtin_amdgcn_fdot2(H2(w0.w), H2(hq[q].w), p0, false);
        p1 = __builtin_amdgcn_fdot2(H2(w1.x), H2(hq[q].x), p1, false);
        p1 = __builtin_amdgcn_fdot2(H2(w1.y), H2(hq[q].y), p1, false);
        p1 = __builtin_amdgcn_fdot2(H2(w1.z), H2(hq[q].z), p1, false);
        p1 = __builtin_amdgcn_fdot2(H2(w1.w), H2(hq[q].w), p1, false);
#else
        unsigned wu0[4]={w0.x,w0.y,w0.z,w0.w}, wu1[4]={w1.x,w1.y,w1.z,w1.w};
        unsigned hu[4]={hq[q].x,hq[q].y,hq[q].z,hq[q].w};
        for (int i2=0;i2<4;i2++){
          half2v hv=H2(hu[i2]);
          half2v a=H2(wu0[i2]), bb2=H2(wu1[i2]);
          p0 += (float)a.x*(float)hv.x + (float)a.y*(float)hv.y;
          p1 += (float)bb2.x*(float)hv.x + (float)bb2.y*(float)hv.y;
        }
#endif
      }
      #pragma unroll
      for (int q=0;q<4;q++){
#if __has_builtin(__builtin_amdgcn_fdot2)
        p2 = __builtin_amdgcn_fdot2(H2(w2q[q].x), H2(hq[q].x), p2, false);
        p2 = __builtin_amdgcn_fdot2(H2(w2q[q].y), H2(hq[q].y), p2, false);
        p2 = __builtin_amdgcn_fdot2(H2(w2q[q].z), H2(hq[q].z), p2, false);
        p2 = __builtin_amdgcn_fdot2(H2(w2q[q].w), H2(hq[q].w), p2, false);
        p3 = __builtin_amdgcn_fdot2(H2(w3q[q].x), H2(hq[q].x), p3, false);
        p3 = __builtin_amdgcn_fdot2(H2(w3q[q].y), H2(hq[q].y), p3, false);
        p3 = __builtin_amdgcn_fdot2(H2(w3q[q].z), H2(hq[q].z), p3, false);
        p3 = __builtin_amdgcn_fdot2(H2(w3q[q].w), H2(hq[q].w), p3, false);
#else
        unsigned wu2[4]={w2q[q].x,w2q[q].y,w2q[q].z,w2q[q].w}, wu3[4]={w3q[q].x,w3q[q].y,w3q[q].z,w3q[q].w};
        unsigned hu[4]={hq[q].x,hq[q].y,hq[q].z,hq[q].w};
        for (int i2=0;i2<4;i2++){
          half2v hv=H2(hu[i2]);
          half2v a=H2(wu2[i2]), bb2=H2(wu3[i2]);
          p2 += (float)a.x*(float)hv.x + (float)a.y*(float)hv.y;
          p3 += (float)bb2.x*(float)hv.x + (float)bb2.y*(float)hv.y;
        }
#endif
      }
      p0 += (sub==0) ? xcur : 0.f;
      p1 += (sub==1) ? xcur : 0.f;
      p2 += (sub==2) ? xcur : 0.f;
      p3 += (sub==3) ? xcur : 0.f;
      p0 += __shfl_xor(p0,1); p0 += __shfl_xor(p0,2);
      p1 += __shfl_xor(p1,1); p1 += __shfl_xor(p1,2);
      p2 += __shfl_xor(p2,1); p2 += __shfl_xor(p2,2);
      p3 += __shfl_xor(p3,1); p3 += __shfl_xor(p3,2);
      float ig=sigf(p0), fg=sigf(p1), gg=tanhfast(p2), og=sigf(p3);
      c = fg*c + ig*gg;
      float h = og*tanhfast(c);
      if (sub == 0){
        h_lds[1-cur][j] = (_Float16)h;
        h_stage[t*HTc + j] = bf16r(h);
      }
      __syncthreads();
    }
  }
  // final flush (last chunk)
  {
    const unsigned* st = (const unsigned*)h_stage;
    unsigned* dst = (unsigned*)hb + (Tc/CH - 1)*(CH*HTc/2);
    #pragma unroll
    for (int i=0;i<CH*HTc/2/512;i++) dst[i*512+tid] = st[i*512+tid];
    if (tid < (CH*HTc/2)%512) dst[(CH*HTc/2/512)*512+tid] = st[(CH*HTc/2/512)*512+tid];
  }
}

extern "C" void kernel_launch(void* const* d_in, const int* in_sizes, int n_in,
                              void* d_out, int out_size, void* d_ws, size_t ws_size,
                              hipStream_t stream)
{
  const int* question_seq=(const int*)d_in[0];
  const int* skill_seq   =(const int*)d_in[1];
  const int* answer_seq  =(const int*)d_in[2];
  const int* hg_q        =(const int*)d_in[3];
  const int* hg_c        =(const int*)d_in[4];
  const int* gcn_src     =(const int*)d_in[5];
  const int* gcn_dst     =(const int*)d_in[6];
  const int* sim_src     =(const int*)d_in[7];
  const int* sim_dst     =(const int*)d_in[8];
  const float* hg_vals_qc=(const float*)d_in[9];
  const float* hg_vals_cq=(const float*)d_in[10];
  const float* sim_vals  =(const float*)d_in[11];
  const float* q_emb     =(const float*)d_in[12];
  const float* s_emb     =(const float*)d_in[13];
  const float* c_emb     =(const float*)d_in[14];
  const float* w_g1=(const float*)d_in[15];
  const float* w_g2=(const float*)d_in[16];
  const float* w_g3=(const float*)d_in[17];
  const float* b_g1=(const float*)d_in[18];
  const float* b_g2=(const float*)d_in[19];
  const float* b_g3=(const float*)d_in[20];
  const float* gcn_w1=(const float*)d_in[21];
  const float* gcn_b1=(const float*)d_in[22];
  const float* gcn_w2=(const float*)d_in[23];
  const float* gcn_b2=(const float*)d_in[24];
  const float* gcn_w3=(const float*)d_in[25];
  const float* gcn_b3=(const float*)d_in[26];
  const float* w_sg1=(const float*)d_in[27];
  const float* w_sg2=(const float*)d_in[28];
  const float* w_qg1=(const float*)d_in[29];
  const float* w_qg3=(const float*)d_in[30];
  const float* b_sg1=(const float*)d_in[31];
  const float* b_sg2=(const float*)d_in[32];
  const float* b_qg1=(const float*)d_in[33];
  const float* b_qg3=(const float*)d_in[34];
  const float* w_ih=(const float*)d_in[35];
  const float* w_hh=(const float*)d_in[36];
  const float* b_ih=(const float*)d_in[37];
  const float* b_hh=(const float*)d_in[38];
  const float* fc1_w=(const float*)d_in[39];
  const float* fc1_b=(const float*)d_in[40];
  const float* fc2_w=(const float*)d_in[41];
  const float* fc2_b=(const float*)d_in[42];
  (void)in_sizes; (void)n_in;
  float* outp = (float*)d_out;

  char* base = (char*)d_ws;
  size_t off = 0;
  auto alloc = [&](size_t bytes)->size_t{ size_t r = off; off = (off + bytes + 255) & ~(size_t)255; return r; };

  size_t XPbytes = (size_t)BTc*G4c*4;
  size_t o_XP     = alloc(XPbytes);
  size_t o_libf   = alloc((size_t)BTc*LINc*2);
  size_t o_hsbf   = alloc((size_t)BTc*HTc*2);
  size_t o_qembbf = alloc((size_t)100096*Dc*2);
  size_t o_bfY    = alloc((size_t)NQc*Dc*2);
  size_t o_wihbf  = alloc((size_t)G4c*LINc*2);
  size_t o_fc1wT  = alloc((size_t)HTc*384*2);
  size_t o_wg3T   = alloc((size_t)Dc*Dc*2);
  size_t o_whhh   = alloc((size_t)G4c*HTc*2);
  size_t o_biasP  = alloc((size_t)G4c*4);
  if (off > ws_size){
    fill_kernel<<<(out_size+255)/256, 256, 0, stream>>>(outp, -1.0f, out_size);
    return;
  }

  char* xp = base + o_XP;
  size_t poff = 0;
  auto pall = [&](size_t bytes)->size_t{ size_t r = poff; poff = (poff + bytes + 255) & ~(size_t)255; return r; };
  size_t p_A       = pall((size_t)NQc*Dc*4);
  size_t p_B       = pall((size_t)NQc*Dc*4);
  size_t p_col_sim = pall((size_t)NNZ_SIMc*4);
  size_t p_val_sim = pall((size_t)NNZ_SIMc*4);
  size_t p_col_hgq = pall((size_t)NNZ_HGc*4);
  size_t p_val_hgq = pall((size_t)NNZ_HGc*4);
  size_t p_col_hgc = pall((size_t)NNZ_HGc*4);
  size_t p_val_hgc = pall((size_t)NNZ_HGc*4);
  size_t p_src_gcn = pall((size_t)NNZ_GCNc*4);
  size_t p_rp_sim  = pall((size_t)(NQc+1)*4);
  size_t p_rp_hgq  = pall((size_t)(NQc+1)*4);
  size_t p_rp_hgc  = pall((size_t)(NSc+1)*4);
  size_t p_rp_gcn  = pall((size_t)(NSc+1)*4);
  size_t p_cnt_sim = pall((size_t)NQc*4);
  size_t p_cnt_hgq = pall((size_t)NQc*4);
  size_t p_cnt_hgc = pall((size_t)NSc*4);
  size_t p_cnt_gcn = pall((size_t)NSc*4);
  size_t p_cnt_end = poff;
  size_t p_bsum    = pall((size_t)4*BS_STRIDE*4);
  size_t p_dinv    = pall((size_t)NSc*4);
  size_t p_onegate = pall((size_t)NSc*Dc*4);
  size_t p_twogate = pall((size_t)NSc*Dc*4);
  size_t p_ssum    = pall((size_t)NSc*Dc*4);
  size_t p_sxA     = pall((size_t)NSc*Dc*4);
  size_t p_sxB     = pall((size_t)NSc*Dc*4);
  size_t p_gxA     = pall((size_t)NSc*Dc*4);
  size_t p_gxB     = pall((size_t)NSc*Dc*4);
  size_t p_htmp    = pall((size_t)NSc*Dc*4);
  size_t p_ogbf    = pall((size_t)NSc*Dc*2);
  size_t p_sxBbf   = pall((size_t)NSc*Dc*2);
  size_t p_ssumbf  = pall((size_t)NSc*Dc*2);
  if (poff > XPbytes){
    fill_kernel<<<(out_size+255)/256, 256, 0, stream>>>(outp, -2.0f, out_size);
    return;
  }

  float* Abuf    = (float*)(xp + p_A);
  float* Bbuf    = (float*)(xp + p_B);
  int*   col_sim = (int*)(xp + p_col_sim);
  float* val_sim = (float*)(xp + p_val_sim);
  int*   col_hgq = (int*)(xp + p_col_hgq);
  float* val_hgq = (float*)(xp + p_val_hgq);
  int*   col_hgc = (int*)(xp + p_col_hgc);
  float* val_hgc = (float*)(xp + p_val_hgc);
  int*   src_gcn = (int*)(xp + p_src_gcn);
  int*   rp_sim  = (int*)(xp + p_rp_sim);
  int*   rp_hgq  = (int*)(xp + p_rp_hgq);
  int*   rp_hgc  = (int*)(xp + p_rp_hgc);
  int*   rp_gcn  = (int*)(xp + p_rp_gcn);
  int*   cnt_sim = (int*)(xp + p_cnt_sim);
  int*   cnt_hgq = (int*)(xp + p_cnt_hgq);
  int*   cnt_hgc = (int*)(xp + p_cnt_hgc);
  int*   cnt_gcn = (int*)(xp + p_cnt_gcn);
  int*   bsum    = (int*)(xp + p_bsum);
  float* dinv    = (float*)(xp + p_dinv);
  float* one_gate= (float*)(xp + p_onegate);
  float* two_gate= (float*)(xp + p_twogate);
  float* ssum    = (float*)(xp + p_ssum);
  float* sxA     = (float*)(xp + p_sxA);
  float* sxB     = (float*)(xp + p_sxB);
  float* gxA     = (float*)(xp + p_gxA);
  float* gxB     = (float*)(xp + p_gxB);
  float* htmp    = (float*)(xp + p_htmp);
  unsigned short* og_bf   = (unsigned short*)(xp + p_ogbf);
  unsigned short* sxB_bf  = (unsigned short*)(xp + p_sxBbf);
  unsigned short* ssum_bf = (unsigned short*)(xp + p_ssumbf);

  float* xpart   = (float*)xp;
  unsigned short* lstm_in_bf = (unsigned short*)(base + o_libf);
  unsigned short* hs_bf      = (unsigned short*)(base + o_hsbf);
  unsigned short* q_emb_bf   = (unsigned short*)(base + o_qembbf);
  unsigned short* bfX        = (unsigned short*)(base + o_qembbf);
  unsigned short* bfY        = (unsigned short*)(base + o_bfY);
  unsigned short* w_ih_bf    = (unsigned short*)(base + o_wihbf);
  unsigned short* fc1_wT     = (unsigned short*)(base + o_fc1wT);
  unsigned short* w_g3T      = (unsigned short*)(base + o_wg3T);
  _Float16*       w_hh_h     = (_Float16*)(base + o_whhh);
  float*          biasP      = (float*)(base + o_biasP);

  auto gemm32 = [&](const float* A, int lda, const float* Bp, float* Cp,
                    unsigned short* Cbf, float* Ccopy, const float* bias,
                    const float* gsrc, int M, int N, int K, int ep){
    dim3 g(N/64, (M+63)/64), b(256);
    gemm_kernel<<<g, b, 0, stream>>>(A, lda, Bp, Cp, Cbf, Ccopy, bias, gsrc, M, N, K, ep);
  };
  auto spmm = [&](const int* rp, const int* col, const float* val, const unsigned short* xb,
                  const float* resid, const float* resid2, float beta,
                  float* y, unsigned short* yb, float* sum, unsigned short* sumbf,
                  float alpha, int nrows){
    spmm_bf_kernel<<<(nrows+3)/4, 256, 0, stream>>>(rp, col, val, xb, resid, resid2, beta, y, yb, sum, sumbf, alpha, nrows);
  };

  // ---- CSR build ----
  hipMemsetAsync(xp + p_cnt_sim, 0, p_cnt_end - p_cnt_sim, stream);
  hist_all_kernel<<<2048, 256, 0, stream>>>(sim_src, cnt_sim, hg_q, cnt_hgq, hg_c, cnt_hgc, gcn_dst, cnt_gcn);
  scan_local_all_kernel<<<200, 1024, 0, stream>>>(cnt_sim, rp_sim, cnt_hgq, rp_hgq,
                                                  cnt_hgc, rp_hgc, cnt_gcn, rp_gcn, bsum, dinv);
  scan_bsum_all_kernel<<<4, 128, 0, stream>>>(bsum);
  scan_add_all_kernel<<<798, 256, 0, stream>>>(rp_sim, cnt_sim, rp_hgq, cnt_hgq,
                                               rp_hgc, cnt_hgc, rp_gcn, cnt_gcn, bsum);
  scatter_all_kernel<<<2048, 256, 0, stream>>>(
      sim_src, sim_dst, sim_vals, cnt_sim, col_sim, val_sim,
      hg_q, hg_c, hg_vals_qc, hg_vals_cq,
      cnt_hgq, col_hgq, val_hgq, cnt_hgc, col_hgc, val_hgc,
      gcn_dst, gcn_src, cnt_gcn, src_gcn);

  // ---- weight converts ----
  cvt_bf16_kernel<<<2048, 256, 0, stream>>>(q_emb, q_emb_bf, (long)(NQc+1)*Dc);
  cvt_weights_kernel<<<1154, 256, 0, stream>>>(w_ih, w_ih_bf, fc1_w, fc1_wT, w_g3, w_g3T,
                                               w_hh, w_hh_h, b_ih, b_hh, biasP);

  // ---- channel 3: three_gate (MFMA) -> Abuf fp32 + bfY bf16; sim conv (fused mean) ----
  {
    dim3 g(1, (NQc+127)/128);
    mfma_gemm_kernel<<<g, 256, 0, stream>>>(q_emb_bf, Dc, q_emb_bf, Dc, Dc, w_g3T,
                                            Abuf, bfY, b_g3, nullptr, q_emb,
                                            nullptr, nullptr, nullptr, NQc, Dc, Dc, 1);
  }
  spmm(rp_sim, col_sim, val_sim, bfY, Abuf, nullptr, 0.f, Bbuf, bfX,    nullptr, nullptr, 1.f, NQc); // e1
  spmm(rp_sim, col_sim, val_sim, bfX, Abuf, Bbuf, 2.f,   Abuf, nullptr, nullptr, nullptr, 1.f, NQc); // three_sum

  // ---- gated skill embeddings (ssum & og_bf fused into first GEMM epilogue) ----
  gemm32(s_emb, Dc, w_g1, one_gate, og_bf, ssum, b_g1, s_emb, NSc, Dc, Dc, 1);
  gemm32(s_emb, Dc, w_g2, two_gate, nullptr, nullptr, b_g2, s_emb, NSc, Dc, Dc, 1);

  // ---- channel 1: hypergraph 2-hop ----
  spmm(rp_hgq, col_hgq, val_hgq, og_bf,  nullptr,  nullptr, 0.f, Bbuf, bfY,    nullptr, nullptr, 1.f, NQc); // m1
  spmm(rp_hgc, col_hgc, val_hgc, bfY,    one_gate, nullptr, 0.f, sxB,  sxB_bf, ssum,    nullptr, 1.f, NSc); // e1
  spmm(rp_hgq, col_hgq, val_hgq, sxB_bf, nullptr,  nullptr, 0.f, Bbuf, bfY,    nullptr, nullptr, 1.f, NQc); // m2
  spmm(rp_hgc, col_hgc, val_hgc, bfY,    sxB,      nullptr, 0.f, sxA,  nullptr, ssum,   ssum_bf, 1.f, NSc); // e2 (+ssum_bf)
  spmm(rp_hgq, col_hgq, val_hgq, ssum_bf, nullptr, nullptr, 0.f, Bbuf, nullptr, nullptr, nullptr, 1.f/3.f, NQc); // one_q

  // ---- channel 2: 3-layer GCN -> gxA ----
  gemm32(two_gate, Dc, gcn_w1, htmp, nullptr, nullptr, nullptr, nullptr, NSc, Dc, Dc, 0);
  gcn_spmm_kernel<<<(NSc+3)/4, 256, 0, stream>>>(rp_gcn, src_gcn, dinv, htmp, gcn_b1, gxA, NSc);
  gemm32(gxA, Dc, gcn_w2, htmp, nullptr, nullptr, nullptr, nullptr, NSc, Dc, Dc, 0);
  gcn_spmm_kernel<<<(NSc+3)/4, 256, 0, stream>>>(rp_gcn, src_gcn, dinv, htmp, gcn_b2, gxB, NSc);
  gemm32(gxB, Dc, gcn_w3, htmp, nullptr, nullptr, nullptr, nullptr, NSc, Dc, Dc, 0);
  gcn_spmm_kernel<<<(NSc+3)/4, 256, 0, stream>>>(rp_gcn, src_gcn, dinv, htmp, gcn_b3, gxA, NSc);

  // ---- gather + gated fusion -> lstm_in_bf ----
  gather_fuse_kernel<<<(BTc+3)/4, 256, 0, stream>>>(
      question_seq, skill_seq, answer_seq,
      ssum, Bbuf, gxA, Abuf,
      s_emb, q_emb, c_emb,
      w_sg1, w_sg2, w_qg1, w_qg3, b_sg1, b_sg2, b_qg1, b_qg3,
      lstm_in_bf);

  // ---- xpart = lstm_in @ w_ihP^T + biasP (MFMA; clobbers phase-A region) ----
  {
    dim3 g(G4c/128, BTc/128);
    mfma_gemm_kernel<<<g, 256, 0, stream>>>(lstm_in_bf, LINc, lstm_in_bf, LINc, LINc, w_ih_bf,
                                            xpart, nullptr, biasP, nullptr, nullptr,
                                            nullptr, nullptr, nullptr, BTc, G4c, LINc, 0);
  }

  // ---- LSTM ----
  lstm_kernel<<<Bc, 512, 0, stream>>>(xpart, w_hh_h, hs_bf);

  // ---- head: fc1+fc2 fused (MFMA ep=3) -> d_out ----
  {
    dim3 g(1, BTc/128);
    mfma_gemm_kernel<<<g, 256, 0, stream>>>(hs_bf, HTc, lstm_in_bf, LINc, HTc, fc1_wT,
                                            nullptr, nullptr, fc1_b, nullptr, nullptr,
                                            fc2_w, fc2_b, outp, BTc, 128, 384, 3);
  }
}

// Round 11
// 1390.007 us; speedup vs baseline: 1.0259x; 1.0259x over previous
//
#include <hip/hip_runtime.h>

#define NQc 100000
#define NSc 2000
#define Dc 128
#define DCc 64
#define HTc 128
#define Bc 128
#define Tc 500
#define BTc (Bc*Tc)
#define NNZ_HGc 300000
#define NNZ_GCNc 64000
#define NNZ_SIMc 1000000
#define LINc 320
#define G4c 512

using bf16x8  = __attribute__((ext_vector_type(8))) short;
using floatx4 = __attribute__((ext_vector_type(4))) float;
typedef _Float16 half2v __attribute__((ext_vector_type(2)));

__device__ __forceinline__ float sigf(float x){ return 1.0f/(1.0f + __expf(-x)); }
__device__ __forceinline__ float tanhfast(float x){ return 2.0f*sigf(2.0f*x) - 1.0f; }

__device__ __forceinline__ unsigned short bf16r(float x){
  unsigned u = __float_as_uint(x);
  unsigned r = (u + 0x7FFFu + ((u>>16)&1u)) >> 16;
  return (unsigned short)r;
}
__device__ __forceinline__ unsigned pack2(float2 v){
  return (unsigned)bf16r(v.x) | ((unsigned)bf16r(v.y) << 16);
}
__device__ __forceinline__ float bflo(unsigned u){ return __uint_as_float(u << 16); }
__device__ __forceinline__ float bfhi(unsigned u){ return __uint_as_float(u & 0xFFFF0000u); }

__device__ __forceinline__ float wredsum(float v){
  #pragma unroll
  for (int off=32; off>0; off>>=1) v += __shfl_xor(v, off, 64);
  return v;
}

__global__ void fill_kernel(float* p, float v, int n){
  int i = blockIdx.x*blockDim.x + threadIdx.x;
  if (i<n) p[i] = v;
}

// ---------------- converts ----------------
__global__ void cvt_bf16_kernel(const float* __restrict__ in, unsigned short* __restrict__ out, long n){
  long i = (long)blockIdx.x*blockDim.x + threadIdx.x;
  long stride = (long)gridDim.x*blockDim.x;
  for (; i<n; i+=stride) out[i] = bf16r(in[i]);
}

// fused small weight converts
__global__ void cvt_weights_kernel(
    const float* __restrict__ w_ih, unsigned short* __restrict__ w_ih_bf,
    const float* __restrict__ fc1_w, unsigned short* __restrict__ fc1_wT,
    const float* __restrict__ w_g3, unsigned short* __restrict__ w_g3T,
    const float* __restrict__ w_hh, _Float16* __restrict__ w_hh_h,
    const float* __restrict__ b_ih, const float* __restrict__ b_hh, float* __restrict__ biasP)
{
  int i = blockIdx.x*blockDim.x + threadIdx.x;
  const int T0 = G4c*LINc;            // 163840
  const int T1 = T0 + 384*HTc;        // +49152
  const int T2 = T1 + Dc*Dc;          // +16384
  const int T3 = T2 + G4c*HTc;        // +65536
  const int T4 = T3 + G4c;            // +512
  if (i < T0){
    int r = i/LINc, c = i%LINc;
    int rp = (r&127)*4 + (r>>7);
    w_ih_bf[(size_t)rp*LINc + c] = bf16r(w_ih[i]);
  } else if (i < T1){
    int j = i - T0; int r = j/HTc, c = j%HTc;
    fc1_wT[(size_t)c*384 + r] = bf16r(fc1_w[j]);
  } else if (i < T2){
    int j = i - T1; int r = j/Dc, c = j%Dc;
    w_g3T[(size_t)c*Dc + r] = bf16r(w_g3[j]);
  } else if (i < T3){
    int j = i - T2;
    w_hh_h[j] = (_Float16)w_hh[j];
  } else if (i < T4){
    int j = i - T3;
    biasP[(j&127)*4 + (j>>7)] = b_ih[j] + b_hh[j];
  }
}

// ---------------- CSR build (fused) ----------------
__global__ void hist_all_kernel(const int* __restrict__ sim_src, int* cnt_sim,
                                const int* __restrict__ hg_q, int* cnt_hgq,
                                const int* __restrict__ hg_c, int* cnt_hgc,
                                const int* __restrict__ gcn_dst, int* cnt_gcn){
  long i = (long)blockIdx.x*blockDim.x + threadIdx.x;
  long stride = (long)gridDim.x*blockDim.x;
  const long T0=NNZ_SIMc, T1=T0+NNZ_HGc, T2=T1+NNZ_HGc, T3=T2+NNZ_GCNc;
  for (; i<T3; i+=stride){
    if (i<T0)      atomicAdd(&cnt_sim[sim_src[i]], 1);
    else if (i<T1) atomicAdd(&cnt_hgq[hg_q[i-T0]], 1);
    else if (i<T2) atomicAdd(&cnt_hgc[hg_c[i-T1]], 1);
    else           atomicAdd(&cnt_gcn[gcn_dst[i-T2]], 1);
  }
}

#define BS_STRIDE 104
__global__ __launch_bounds__(1024) void scan_local_all_kernel(
    const int* __restrict__ cnt_sim, int* rp_sim,
    const int* __restrict__ cnt_hgq, int* rp_hgq,
    const int* __restrict__ cnt_hgc, int* rp_hgc,
    const int* __restrict__ cnt_gcn, int* rp_gcn,
    int* __restrict__ bsum, float* __restrict__ dinv)
{
  __shared__ int buf[1024];
  int b = blockIdx.x, tid = threadIdx.x;
  const int* cnt; int* rp; int* bs; int n; int lb; int seg;
  if (b < 98)      { seg=0; cnt=cnt_sim; rp=rp_sim; n=NQc; lb=b; }
  else if (b <196) { seg=1; cnt=cnt_hgq; rp=rp_hgq; n=NQc; lb=b-98; }
  else if (b <198) { seg=2; cnt=cnt_hgc; rp=rp_hgc; n=NSc; lb=b-196; }
  else             { seg=3; cnt=cnt_gcn; rp=rp_gcn; n=NSc; lb=b-198; }
  bs = bsum + seg*BS_STRIDE;
  int i = lb*1024 + tid;
  int v = (i<n) ? cnt[i] : 0;
  if (seg==3 && i<n) dinv[i] = rsqrtf((float)v + 1.0f);
  buf[tid] = v;
  __syncthreads();
  for (int off=1; off<1024; off<<=1){
    int t = (tid>=off) ? buf[tid-off] : 0;
    __syncthreads();
    buf[tid] += t;
    __syncthreads();
  }
  if (i<n) rp[i] = buf[tid] - v;
  if (tid==1023) bs[lb] = buf[1023];
}
__global__ __launch_bounds__(128) void scan_bsum_all_kernel(int* bsum){
  __shared__ int s[128];
  int seg = blockIdx.x, tid = threadIdx.x;
  int nb = (seg<2) ? 98 : 2;
  int* bs = bsum + seg*BS_STRIDE;
  int v = (tid<nb) ? bs[tid] : 0;
  s[tid] = v;
  __syncthreads();
  for (int off=1; off<128; off<<=1){
    int t = (tid>=off) ? s[tid-off] : 0;
    __syncthreads();
    s[tid] += t;
    __syncthreads();
  }
  if (tid<nb) bs[tid] = s[tid] - v;
  if (tid==0) bs[nb] = s[127];
}
__global__ void scan_add_all_kernel(
    int* rp_sim, int* cnt_sim, int* rp_hgq, int* cnt_hgq,
    int* rp_hgc, int* cnt_hgc, int* rp_gcn, int* cnt_gcn,
    const int* __restrict__ bsum)
{
  int b = blockIdx.x, tid = threadIdx.x;
  int* rp; int* cur; const int* bs; int n; int lb; int nb;
  if (b < 391)      { rp=rp_sim; cur=cnt_sim; bs=bsum;               n=NQc; lb=b;     nb=98; }
  else if (b < 782) { rp=rp_hgq; cur=cnt_hgq; bs=bsum+BS_STRIDE;     n=NQc; lb=b-391; nb=98; }
  else if (b < 790) { rp=rp_hgc; cur=cnt_hgc; bs=bsum+2*BS_STRIDE;   n=NSc; lb=b-782; nb=2; }
  else              { rp=rp_gcn; cur=cnt_gcn; bs=bsum+3*BS_STRIDE;   n=NSc; lb=b-790; nb=2; }
  int i = lb*256 + tid;
  if (i<n){ int r = rp[i] + bs[i>>10]; rp[i]=r; cur[i]=r; }
  if (lb==0 && tid==0) rp[n] = bs[nb];
}

__global__ void scatter_all_kernel(
    const int* __restrict__ sim_src, const int* __restrict__ sim_dst, const float* __restrict__ sim_vals,
    int* cur_sim, int* col_sim, float* val_sim,
    const int* __restrict__ hg_q, const int* __restrict__ hg_c,
    const float* __restrict__ hg_vals_qc, const float* __restrict__ hg_vals_cq,
    int* cur_hgq, int* col_hgq, float* val_hgq,
    int* cur_hgc, int* col_hgc, float* val_hgc,
    const int* __restrict__ gcn_dst, const int* __restrict__ gcn_src,
    int* cur_gcn, int* src_gcn)
{
  long i = (long)blockIdx.x*blockDim.x + threadIdx.x;
  long stride = (long)gridDim.x*blockDim.x;
  const long T0=NNZ_SIMc, T1=T0+NNZ_HGc, T2=T1+NNZ_HGc, T3=T2+NNZ_GCNc;
  for (; i<T3; i+=stride){
    if (i<T0){
      int r = sim_src[i]; int p = atomicAdd(&cur_sim[r],1);
      col_sim[p] = sim_dst[i]; val_sim[p] = sim_vals[i];
    } else if (i<T1){
      long j=i-T0; int r = hg_q[j]; int p = atomicAdd(&cur_hgq[r],1);
      col_hgq[p] = hg_c[j]; val_hgq[p] = hg_vals_qc[j];
    } else if (i<T2){
      long j=i-T1; int r = hg_c[j]; int p = atomicAdd(&cur_hgc[r],1);
      col_hgc[p] = hg_q[j]; val_hgc[p] = hg_vals_cq[j];
    } else {
      long j=i-T2; int r = gcn_dst[j]; int p = atomicAdd(&cur_gcn[r],1);
      src_gcn[p] = gcn_src[j];
    }
  }
}

// ---------------- fp32 GEMM (small NS-sized matmuls) ----------------
#define BM 64
#define BN 64
#define BK 16
__global__ __launch_bounds__(256) void gemm_kernel(
    const float* __restrict__ A, int lda,
    const float* __restrict__ Bm, float* __restrict__ C,
    unsigned short* __restrict__ Cbf, float* __restrict__ Ccopy,
    const float* __restrict__ bias, const float* __restrict__ gsrc,
    int M, int N, int K, int ep)
{
  __shared__ float As[BM][BK+4];
  __shared__ float Bs[BK][BN+4];
  int tid = threadIdx.x;
  int tx = tid & 15, ty = tid >> 4;
  int mBase = blockIdx.y*BM, nBase = blockIdx.x*BN;
  float acc[4][4];
  #pragma unroll
  for (int i=0;i<4;i++)
    #pragma unroll
    for (int j=0;j<4;j++) acc[i][j]=0.f;
  int arow = tid>>2, ac4 = tid&3;
  for (int kt=0; kt<K; kt+=BK){
    {
      int m = mBase + arow;
      float4 v = make_float4(0.f,0.f,0.f,0.f);
      if (m < M) v = *(const float4*)(A + (size_t)m*lda + kt + ac4*4);
      *(float4*)&As[arow][ac4*4] = v;
    }
    {
      int kr = tid>>4, c4 = tid&15;
      float4 v = *(const float4*)(Bm + (size_t)(kt+kr)*N + nBase + c4*4);
      *(float4*)&Bs[kr][c4*4] = v;
    }
    __syncthreads();
    #pragma unroll
    for (int k=0;k<BK;k++){
      float a0=As[ty*4+0][k],a1=As[ty*4+1][k],a2=As[ty*4+2][k],a3=As[ty*4+3][k];
      float b0=Bs[k][tx*4+0],b1=Bs[k][tx*4+1],b2=Bs[k][tx*4+2],b3=Bs[k][tx*4+3];
      acc[0][0]+=a0*b0; acc[0][1]+=a0*b1; acc[0][2]+=a0*b2; acc[0][3]+=a0*b3;
      acc[1][0]+=a1*b0; acc[1][1]+=a1*b1; acc[1][2]+=a1*b2; acc[1][3]+=a1*b3;
      acc[2][0]+=a2*b0; acc[2][1]+=a2*b1; acc[2][2]+=a2*b2; acc[2][3]+=a2*b3;
      acc[3][0]+=a3*b0; acc[3][1]+=a3*b1; acc[3][2]+=a3*b2; acc[3][3]+=a3*b3;
    }
    __syncthreads();
  }
  #pragma unroll
  for (int i=0;i<4;i++){
    int m = mBase + ty*4 + i;
    if (m >= M) continue;
    #pragma unroll
    for (int j=0;j<4;j++){
      int n = nBase + tx*4 + j;
      float v = acc[i][j];
      if (bias)  v += bias[n];
      if (ep==1)      v = gsrc[(size_t)m*N + n] * sigf(v);
      C[(size_t)m*N + n] = v;
      if (Cbf)   Cbf[(size_t)m*N + n] = bf16r(v);
      if (Ccopy) Ccopy[(size_t)m*N + n] = v;
    }
  }
}

// ---------------- MFMA bf16 GEMM ----------------
// ep: 0 = +bias(+bias2); 1 = gsrc*sigmoid(acc+bias); 2 = relu(acc+bias);
// ep 3 = fused head: out[row] = sig( relu(acc+bias)·fc2w + fc2b ), no C store.
// C (fp32) optional; Cbf (bf16) optional.
__global__ __launch_bounds__(256) void mfma_gemm_kernel(
    const unsigned short* __restrict__ A1, int lda1,
    const unsigned short* __restrict__ A2, int lda2, int ksplit,
    const unsigned short* __restrict__ Bt,
    float* __restrict__ C, unsigned short* __restrict__ Cbf,
    const float* __restrict__ bias, const float* __restrict__ bias2,
    const float* __restrict__ gsrc,
    const float* __restrict__ fc2w, const float* __restrict__ fc2b, float* __restrict__ outp,
    int M, int N, int K, int ep)
{
  __shared__ unsigned short Asm[128*64];
  __shared__ unsigned short Bsm[128*64];
  __shared__ float rps[2][128];
  int tid = threadIdx.x;
  int wave = tid>>6, lane = tid&63;
  int quad = lane>>4, l16 = lane&15;
  int m0 = blockIdx.y*128, n0 = blockIdx.x*128;
  int wm = (wave&1)*64, wn = (wave>>1)*64;
  floatx4 acc[4][4];
  #pragma unroll
  for (int i=0;i<4;i++)
    #pragma unroll
    for (int j=0;j<4;j++) acc[i][j] = (floatx4){0.f,0.f,0.f,0.f};

  for (int kt=0; kt<K; kt+=64){
    #pragma unroll
    for (int i=0;i<4;i++){
      int idx = i*256 + tid;
      int row = idx>>3, blk = idx&7;
      int kcol = kt + blk*8;
      {
        const unsigned short* src = (kcol < ksplit)
            ? (A1 + (size_t)(m0+row)*lda1 + kcol)
            : (A2 + (size_t)(m0+row)*lda2 + (kcol - ksplit));
        float4 v = *(const float4*)src;
        *(float4*)&Asm[row*64 + ((blk ^ (row&7))<<3)] = v;
      }
      {
        const unsigned short* src = Bt + (size_t)(n0+row)*K + kcol;
        float4 v = *(const float4*)src;
        *(float4*)&Bsm[row*64 + ((blk ^ (row&7))<<3)] = v;
      }
    }
    __syncthreads();
    #pragma unroll
    for (int ks=0; ks<2; ks++){
      bf16x8 af[4], bfr[4];
      #pragma unroll
      for (int mt=0;mt<4;mt++){
        int row = wm + mt*16 + l16;
        int blk = ks*4 + quad;
        af[mt] = *(const bf16x8*)&Asm[row*64 + ((blk ^ (row&7))<<3)];
      }
      #pragma unroll
      for (int nt=0;nt<4;nt++){
        int row = wn + nt*16 + l16;
        int blk = ks*4 + quad;
        bfr[nt] = *(const bf16x8*)&Bsm[row*64 + ((blk ^ (row&7))<<3)];
      }
      #pragma unroll
      for (int mt=0;mt<4;mt++)
        #pragma unroll
        for (int nt=0;nt<4;nt++)
          acc[mt][nt] = __builtin_amdgcn_mfma_f32_16x16x32_bf16(af[mt], bfr[nt], acc[mt][nt], 0,0,0);
    }
    __syncthreads();
  }
  if (ep == 3){
    float fw[4], fb[4];
    #pragma unroll
    for (int nt=0;nt<4;nt++){ int col = wn + nt*16 + l16; fw[nt] = fc2w[col]; fb[nt] = bias[col]; }
    #pragma unroll
    for (int mt=0;mt<4;mt++){
      #pragma unroll
      for (int r=0;r<4;r++){
        float s = 0.f;
        #pragma unroll
        for (int nt=0;nt<4;nt++){
          float v = acc[mt][nt][r] + fb[nt];
          v = fmaxf(v, 0.f);
          s += v*fw[nt];
        }
        s += __shfl_xor(s,1); s += __shfl_xor(s,2); s += __shfl_xor(s,4); s += __shfl_xor(s,8);
        if (l16 == 0) rps[wave>>1][wm + mt*16 + quad*4 + r] = s;
      }
    }
    __syncthreads();
    if (tid < 128){
      int row = m0 + tid;
      if (row < M) outp[row] = sigf(rps[0][tid] + rps[1][tid] + fc2b[0]);
    }
    return;
  }
  #pragma unroll
  for (int mt=0;mt<4;mt++){
    #pragma unroll
    for (int nt=0;nt<4;nt++){
      int col = n0 + wn + nt*16 + l16;
      #pragma unroll
      for (int r=0;r<4;r++){
        int row = m0 + wm + mt*16 + quad*4 + r;
        if (row < M){
          float v = acc[mt][nt][r];
          if (bias)  v += bias[col];
          if (bias2) v += bias2[col];
          if (ep==1)      v = gsrc[(size_t)row*N + col] * sigf(v);
          else if (ep==2) v = fmaxf(v, 0.f);
          if (C)   C[(size_t)row*N + col] = v;
          if (Cbf) Cbf[(size_t)row*N + col] = bf16r(v);
        }
      }
    }
  }
}

// ---------------- SpMM (CSR, wave/row, D=128, bf16 gathers, unroll-4) ----------------
// acc = alpha*(A@x_bf) + residF(f32) + residB(bf16) + beta*residB2(bf16)
// outputs: y(f32,opt), ybf(bf16,opt); sumbuf(f32,opt) += acc, sumbf(bf16 copy of sum,opt)
__global__ __launch_bounds__(256) void spmm_bf_kernel(
    const int* __restrict__ rowptr, const int* __restrict__ col, const float* __restrict__ val,
    const unsigned short* __restrict__ xbf,
    const float* __restrict__ residF,
    const unsigned short* __restrict__ residB,
    const unsigned short* __restrict__ residB2, float beta,
    float* __restrict__ y, unsigned short* __restrict__ ybf,
    float* __restrict__ sumbuf, unsigned short* __restrict__ sumbf,
    float alpha, int nrows)
{
  int w = (int)((blockIdx.x*(unsigned)blockDim.x + threadIdx.x) >> 6);
  int lane = threadIdx.x & 63;
  if (w >= nrows) return;
  int beg = rowptr[w], end = rowptr[w+1];
  const unsigned* x2 = (const unsigned*)xbf;
  float ax=0.f, ay=0.f;
  int k = beg;
  for (; k+4 <= end; k+=4){
    int c0=col[k], c1=col[k+1], c2=col[k+2], c3=col[k+3];
    float v0=val[k], v1=val[k+1], v2=val[k+2], v3=val[k+3];
    unsigned u0 = x2[(size_t)c0*64 + lane];
    unsigned u1 = x2[(size_t)c1*64 + lane];
    unsigned u2 = x2[(size_t)c2*64 + lane];
    unsigned u3 = x2[(size_t)c3*64 + lane];
    ax += v0*bflo(u0); ay += v0*bfhi(u0);
    ax += v1*bflo(u1); ay += v1*bfhi(u1);
    ax += v2*bflo(u2); ay += v2*bfhi(u2);
    ax += v3*bflo(u3); ay += v3*bfhi(u3);
  }
  for (; k<end; k++){
    int c = col[k]; float v = val[k];
    unsigned u = x2[(size_t)c*64 + lane];
    ax += v*bflo(u); ay += v*bfhi(u);
  }
  ax*=alpha; ay*=alpha;
  if (residF){ float2 r = ((const float2*)residF)[(size_t)w*64+lane]; ax+=r.x; ay+=r.y; }
  if (residB){ unsigned u = ((const unsigned*)residB)[(size_t)w*64+lane]; ax+=bflo(u); ay+=bfhi(u); }
  if (residB2){ unsigned u = ((const unsigned*)residB2)[(size_t)w*64+lane]; ax+=beta*bflo(u); ay+=beta*bfhi(u); }
  float2 o; o.x=ax; o.y=ay;
  if (y)   ((float2*)y)[(size_t)w*64+lane] = o;
  if (ybf) ((unsigned*)ybf)[(size_t)w*64+lane] = pack2(o);
  if (sumbuf){
    float2 s = ((float2*)sumbuf)[(size_t)w*64+lane];
    s.x+=ax; s.y+=ay;
    ((float2*)sumbuf)[(size_t)w*64+lane] = s;
    if (sumbf) ((unsigned*)sumbf)[(size_t)w*64+lane] = pack2(s);
  }
}

__global__ __launch_bounds__(256) void gcn_spmm_kernel(
    const int* __restrict__ rowptr, const int* __restrict__ src, const float* __restrict__ dinv,
    const float* __restrict__ h, const float* __restrict__ bias, float* __restrict__ out, int nrows)
{
  int w = (int)((blockIdx.x*(unsigned)blockDim.x + threadIdx.x) >> 6);
  int lane = threadIdx.x & 63;
  if (w >= nrows) return;
  int beg = rowptr[w], end = rowptr[w+1];
  const float2* h2 = (const float2*)h;
  float dr = dinv[w];
  float2 self = h2[(size_t)w*64+lane];
  float ax = dr*self.x, ay = dr*self.y;
  int k = beg;
  for (; k+4 <= end; k+=4){
    int s0=src[k], s1=src[k+1], s2=src[k+2], s3=src[k+3];
    float d0=dinv[s0], d1=dinv[s1], d2=dinv[s2], d3=dinv[s3];
    float2 h0=h2[(size_t)s0*64+lane], h1v=h2[(size_t)s1*64+lane];
    float2 h2v=h2[(size_t)s2*64+lane], h3=h2[(size_t)s3*64+lane];
    ax += d0*h0.x + d1*h1v.x + d2*h2v.x + d3*h3.x;
    ay += d0*h0.y + d1*h1v.y + d2*h2v.y + d3*h3.y;
  }
  for (; k<end; k++){
    int s = src[k]; float ds = dinv[s];
    float2 hv = h2[(size_t)s*64+lane];
    ax += ds*hv.x; ay += ds*hv.y;
  }
  ax*=dr; ay*=dr;
  float2 b2 = ((const float2*)bias)[lane];
  float2 o; o.x = fmaxf(ax + b2.x, 0.f); o.y = fmaxf(ay + b2.y, 0.f);
  ((float2*)out)[(size_t)w*64+lane] = o;
}

// ---------------- gather + gated fusion -> lstm_in_bf [BT,320] bf16 ----------------
// one_q / three_sum gathered as bf16 rows (256 B), skill channel fp32 (tiny tables, L2-hot)
__global__ __launch_bounds__(256) void gather_fuse_kernel(
    const int* __restrict__ q_seq, const int* __restrict__ s_seq, const int* __restrict__ a_seq,
    const float* __restrict__ skill_sum, const unsigned short* __restrict__ one_q_bf,
    const float* __restrict__ two_skill, const unsigned short* __restrict__ three_sum_bf,
    const float* __restrict__ s_emb, const float* __restrict__ q_emb, const float* __restrict__ c_emb,
    const float* __restrict__ w_sg1, const float* __restrict__ w_sg2,
    const float* __restrict__ w_qg1, const float* __restrict__ w_qg3,
    const float* __restrict__ b_sg1, const float* __restrict__ b_sg2,
    const float* __restrict__ b_qg1, const float* __restrict__ b_qg3,
    unsigned short* __restrict__ lstm_in_bf)
{
  int idx = (int)((blockIdx.x*(unsigned)blockDim.x + threadIdx.x) >> 6);
  int lane = threadIdx.x & 63;
  if (idx >= BTc) return;
  int q = q_seq[idx], s = s_seq[idx], a = a_seq[idx];
  float2 obs, tbs, obq, tbq;
  if (s < NSc){
    obs = ((const float2*)(skill_sum + (size_t)s*Dc))[lane];
    obs.x *= (1.f/3.f); obs.y *= (1.f/3.f);
    tbs = ((const float2*)(two_skill + (size_t)s*Dc))[lane];
  } else {
    obs = ((const float2*)(s_emb + (size_t)NSc*Dc))[lane];
    tbs = obs;
  }
  if (q < NQc){
    unsigned u1 = ((const unsigned*)(one_q_bf + (size_t)q*Dc))[lane];
    obq.x = bflo(u1); obq.y = bfhi(u1);
    unsigned u2 = ((const unsigned*)(three_sum_bf + (size_t)q*Dc))[lane];
    tbq.x = bflo(u2)*(1.f/3.f); tbq.y = bfhi(u2)*(1.f/3.f);
  } else {
    obq = ((const float2*)(q_emb + (size_t)NQc*Dc))[lane];
    tbq = obq;
  }
  float2 w1 = ((const float2*)w_sg1)[lane];
  float2 w2 = ((const float2*)w_sg2)[lane];
  float2 w3 = ((const float2*)w_qg1)[lane];
  float2 w4 = ((const float2*)w_qg3)[lane];
  float p1 = wredsum(obs.x*w1.x + obs.y*w1.y);
  float p2 = wredsum(tbs.x*w2.x + tbs.y*w2.y);
  float p3 = wredsum(obq.x*w3.x + obq.y*w3.y);
  float p4 = wredsum(tbq.x*w4.x + tbq.y*w4.y);
  float g1 = sigf(p1 + b_sg1[0]);
  float g2 = sigf(p2 + b_sg2[0]);
  float g3 = sigf(p3 + b_qg1[0]);
  float g4 = sigf(p4 + b_qg3[0]);
  float2 fs, fq;
  fs.x = g1*obs.x + g2*tbs.x; fs.y = g1*obs.y + g2*tbs.y;
  fq.x = g3*obq.x + g4*tbq.x; fq.y = g3*obq.y + g4*tbq.y;
  unsigned* rowb = (unsigned*)(lstm_in_bf + (size_t)idx*LINc);
  rowb[lane]      = pack2(fq);
  rowb[64 + lane] = pack2(fs);
  if (lane < 32){
    float2 cv = ((const float2*)(c_emb + (size_t)a*DCc))[lane];
    rowb[128 + lane] = pack2(cv);
  }
}

// ---------------- LSTM (round-6 variant — measured best 448 µs) ----------------
// 512 threads: j = tid>>2 (hidden), sub = tid&3 (k-chunk of 32). Weights stream from L2.
__global__ __launch_bounds__(512, 2) void lstm_kernel(
    const float* __restrict__ xpart, const _Float16* __restrict__ w_hh_h,
    unsigned short* __restrict__ hs_bf)
{
  __shared__ __align__(16) _Float16 h_lds[2][HTc];
  int b = blockIdx.x, tid = threadIdx.x;
  int j = tid >> 2, sub = tid & 3;
  half2v w[4][16];
  #pragma unroll
  for (int g=0; g<4; g++){
    const half2v* wp = (const half2v*)(w_hh_h + (size_t)(g*128 + j)*HTc + sub*32);
    #pragma unroll
    for (int i=0;i<16;i++) w[g][i] = wp[i];
  }
  if (tid < HTc) h_lds[0][tid] = (_Float16)0.f;
  float c = 0.f;
  __syncthreads();
  const float* xp = xpart + (size_t)b*Tc*G4c;
  unsigned short* hb = hs_bf + (size_t)b*Tc*HTc;
  float xcur = xp[tid];
  for (int t=0; t<Tc; t++){
    int tn = (t+1 < Tc) ? t+1 : Tc-1;
    float xnext = xp[(size_t)tn*G4c + tid];
    int cur = t & 1;
    float4 hv[4];
    const float4* hsrc = (const float4*)&h_lds[cur][sub*32];
    #pragma unroll
    for (int i=0;i<4;i++) hv[i] = hsrc[i];
    const half2v* hh = (const half2v*)hv;
    float p0=0.f,p1=0.f,p2=0.f,p3=0.f;
    #pragma unroll
    for (int i=0;i<16;i++){
      half2v h2 = hh[i];
#if __has_builtin(__builtin_amdgcn_fdot2)
      p0 = __builtin_amdgcn_fdot2(w[0][i], h2, p0, false);
      p1 = __builtin_amdgcn_fdot2(w[1][i], h2, p1, false);
      p2 = __builtin_amdgcn_fdot2(w[2][i], h2, p2, false);
      p3 = __builtin_amdgcn_fdot2(w[3][i], h2, p3, false);
#else
      p0 += (float)w[0][i].x*(float)h2.x + (float)w[0][i].y*(float)h2.y;
      p1 += (float)w[1][i].x*(float)h2.x + (float)w[1][i].y*(float)h2.y;
      p2 += (float)w[2][i].x*(float)h2.x + (float)w[2][i].y*(float)h2.y;
      p3 += (float)w[3][i].x*(float)h2.x + (float)w[3][i].y*(float)h2.y;
#endif
    }
    if (sub==0) p0 += xcur; else if (sub==1) p1 += xcur; else if (sub==2) p2 += xcur; else p3 += xcur;
    p0 += __shfl_xor(p0,1); p0 += __shfl_xor(p0,2);
    p1 += __shfl_xor(p1,1); p1 += __shfl_xor(p1,2);
    p2 += __shfl_xor(p2,1); p2 += __shfl_xor(p2,2);
    p3 += __shfl_xor(p3,1); p3 += __shfl_xor(p3,2);
    float ig=sigf(p0), fg=sigf(p1), gg=tanhfast(p2), og=sigf(p3);
    c = fg*c + ig*gg;
    float h = og*tanhfast(c);
    if (sub == 0){
      h_lds[1-cur][j] = (_Float16)h;
      hb[(size_t)t*HTc + j] = bf16r(h);
    }
    __syncthreads();
    xcur = xnext;
  }
}

extern "C" void kernel_launch(void* const* d_in, const int* in_sizes, int n_in,
                              void* d_out, int out_size, void* d_ws, size_t ws_size,
                              hipStream_t stream)
{
  const int* question_seq=(const int*)d_in[0];
  const int* skill_seq   =(const int*)d_in[1];
  const int* answer_seq  =(const int*)d_in[2];
  const int* hg_q        =(const int*)d_in[3];
  const int* hg_c        =(const int*)d_in[4];
  const int* gcn_src     =(const int*)d_in[5];
  const int* gcn_dst     =(const int*)d_in[6];
  const int* sim_src     =(const int*)d_in[7];
  const int* sim_dst     =(const int*)d_in[8];
  const float* hg_vals_qc=(const float*)d_in[9];
  const float* hg_vals_cq=(const float*)d_in[10];
  const float* sim_vals  =(const float*)d_in[11];
  const float* q_emb     =(const float*)d_in[12];
  const float* s_emb     =(const float*)d_in[13];
  const float* c_emb     =(const float*)d_in[14];
  const float* w_g1=(const float*)d_in[15];
  const float* w_g2=(const float*)d_in[16];
  const float* w_g3=(const float*)d_in[17];
  const float* b_g1=(const float*)d_in[18];
  const float* b_g2=(const float*)d_in[19];
  const float* b_g3=(const float*)d_in[20];
  const float* gcn_w1=(const float*)d_in[21];
  const float* gcn_b1=(const float*)d_in[22];
  const float* gcn_w2=(const float*)d_in[23];
  const float* gcn_b2=(const float*)d_in[24];
  const float* gcn_w3=(const float*)d_in[25];
  const float* gcn_b3=(const float*)d_in[26];
  const float* w_sg1=(const float*)d_in[27];
  const float* w_sg2=(const float*)d_in[28];
  const float* w_qg1=(const float*)d_in[29];
  const float* w_qg3=(const float*)d_in[30];
  const float* b_sg1=(const float*)d_in[31];
  const float* b_sg2=(const float*)d_in[32];
  const float* b_qg1=(const float*)d_in[33];
  const float* b_qg3=(const float*)d_in[34];
  const float* w_ih=(const float*)d_in[35];
  const float* w_hh=(const float*)d_in[36];
  const float* b_ih=(const float*)d_in[37];
  const float* b_hh=(const float*)d_in[38];
  const float* fc1_w=(const float*)d_in[39];
  const float* fc1_b=(const float*)d_in[40];
  const float* fc2_w=(const float*)d_in[41];
  const float* fc2_b=(const float*)d_in[42];
  (void)in_sizes; (void)n_in;
  float* outp = (float*)d_out;

  char* base = (char*)d_ws;
  size_t off = 0;
  auto alloc = [&](size_t bytes)->size_t{ size_t r = off; off = (off + bytes + 255) & ~(size_t)255; return r; };

  size_t XPbytes = (size_t)BTc*G4c*4;
  size_t o_XP     = alloc(XPbytes);
  size_t o_libf   = alloc((size_t)BTc*LINc*2);
  size_t o_hsbf   = alloc((size_t)BTc*HTc*2);
  size_t o_qembbf = alloc((size_t)100096*Dc*2);      // q_emb bf16; freed -> (nothing reuses; kept)
  size_t o_wihbf  = alloc((size_t)G4c*LINc*2);
  size_t o_fc1wT  = alloc((size_t)HTc*384*2);
  size_t o_wg3T   = alloc((size_t)Dc*Dc*2);
  size_t o_whhh   = alloc((size_t)G4c*HTc*2);
  size_t o_biasP  = alloc((size_t)G4c*4);
  if (off > ws_size){
    fill_kernel<<<(out_size+255)/256, 256, 0, stream>>>(outp, -1.0f, out_size);
    return;
  }

  char* xp = base + o_XP;
  size_t poff = 0;
  auto pall = [&](size_t bytes)->size_t{ size_t r = poff; poff = (poff + bytes + 255) & ~(size_t)255; return r; };
  size_t p_bfY     = pall((size_t)NQc*Dc*2);   // 25.6 MB
  size_t p_bfX     = pall((size_t)NQc*Dc*2);   // 25.6 MB
  size_t p_bfZ     = pall((size_t)NQc*Dc*2);   // 25.6 MB
  size_t p_col_sim = pall((size_t)NNZ_SIMc*4);
  size_t p_val_sim = pall((size_t)NNZ_SIMc*4);
  size_t p_col_hgq = pall((size_t)NNZ_HGc*4);
  size_t p_val_hgq = pall((size_t)NNZ_HGc*4);
  size_t p_col_hgc = pall((size_t)NNZ_HGc*4);
  size_t p_val_hgc = pall((size_t)NNZ_HGc*4);
  size_t p_src_gcn = pall((size_t)NNZ_GCNc*4);
  size_t p_rp_sim  = pall((size_t)(NQc+1)*4);
  size_t p_rp_hgq  = pall((size_t)(NQc+1)*4);
  size_t p_rp_hgc  = pall((size_t)(NSc+1)*4);
  size_t p_rp_gcn  = pall((size_t)(NSc+1)*4);
  size_t p_cnt_sim = pall((size_t)NQc*4);
  size_t p_cnt_hgq = pall((size_t)NQc*4);
  size_t p_cnt_hgc = pall((size_t)NSc*4);
  size_t p_cnt_gcn = pall((size_t)NSc*4);
  size_t p_cnt_end = poff;
  size_t p_bsum    = pall((size_t)4*BS_STRIDE*4);
  size_t p_dinv    = pall((size_t)NSc*4);
  size_t p_onegate = pall((size_t)NSc*Dc*4);
  size_t p_twogate = pall((size_t)NSc*Dc*4);
  size_t p_ssum    = pall((size_t)NSc*Dc*4);
  size_t p_sxA     = pall((size_t)NSc*Dc*4);
  size_t p_sxB     = pall((size_t)NSc*Dc*4);
  size_t p_gxA     = pall((size_t)NSc*Dc*4);
  size_t p_gxB     = pall((size_t)NSc*Dc*4);
  size_t p_htmp    = pall((size_t)NSc*Dc*4);
  size_t p_ogbf    = pall((size_t)NSc*Dc*2);
  size_t p_sxBbf   = pall((size_t)NSc*Dc*2);
  size_t p_ssumbf  = pall((size_t)NSc*Dc*2);
  if (poff > XPbytes){
    fill_kernel<<<(out_size+255)/256, 256, 0, stream>>>(outp, -2.0f, out_size);
    return;
  }

  unsigned short* bfY = (unsigned short*)(xp + p_bfY);
  unsigned short* bfX = (unsigned short*)(xp + p_bfX);
  unsigned short* bfZ = (unsigned short*)(xp + p_bfZ);
  int*   col_sim = (int*)(xp + p_col_sim);
  float* val_sim = (float*)(xp + p_val_sim);
  int*   col_hgq = (int*)(xp + p_col_hgq);
  float* val_hgq = (float*)(xp + p_val_hgq);
  int*   col_hgc = (int*)(xp + p_col_hgc);
  float* val_hgc = (float*)(xp + p_val_hgc);
  int*   src_gcn = (int*)(xp + p_src_gcn);
  int*   rp_sim  = (int*)(xp + p_rp_sim);
  int*   rp_hgq  = (int*)(xp + p_rp_hgq);
  int*   rp_hgc  = (int*)(xp + p_rp_hgc);
  int*   rp_gcn  = (int*)(xp + p_rp_gcn);
  int*   cnt_sim = (int*)(xp + p_cnt_sim);
  int*   cnt_hgq = (int*)(xp + p_cnt_hgq);
  int*   cnt_hgc = (int*)(xp + p_cnt_hgc);
  int*   cnt_gcn = (int*)(xp + p_cnt_gcn);
  int*   bsum    = (int*)(xp + p_bsum);
  float* dinv    = (float*)(xp + p_dinv);
  float* one_gate= (float*)(xp + p_onegate);
  float* two_gate= (float*)(xp + p_twogate);
  float* ssum    = (float*)(xp + p_ssum);
  float* sxA     = (float*)(xp + p_sxA);
  float* sxB     = (float*)(xp + p_sxB);
  float* gxA     = (float*)(xp + p_gxA);
  float* gxB     = (float*)(xp + p_gxB);
  float* htmp    = (float*)(xp + p_htmp);
  unsigned short* og_bf   = (unsigned short*)(xp + p_ogbf);
  unsigned short* sxB_bf  = (unsigned short*)(xp + p_sxBbf);
  unsigned short* ssum_bf = (unsigned short*)(xp + p_ssumbf);

  float* xpart   = (float*)xp;
  unsigned short* lstm_in_bf = (unsigned short*)(base + o_libf);
  unsigned short* hs_bf      = (unsigned short*)(base + o_hsbf);
  unsigned short* q_emb_bf   = (unsigned short*)(base + o_qembbf);
  unsigned short* w_ih_bf    = (unsigned short*)(base + o_wihbf);
  unsigned short* fc1_wT     = (unsigned short*)(base + o_fc1wT);
  unsigned short* w_g3T      = (unsigned short*)(base + o_wg3T);
  _Float16*       w_hh_h     = (_Float16*)(base + o_whhh);
  float*          biasP      = (float*)(base + o_biasP);

  auto gemm32 = [&](const float* A, int lda, const float* Bp, float* Cp,
                    unsigned short* Cbf, float* Ccopy, const float* bias,
                    const float* gsrc, int M, int N, int K, int ep){
    dim3 g(N/64, (M+63)/64), b(256);
    gemm_kernel<<<g, b, 0, stream>>>(A, lda, Bp, Cp, Cbf, Ccopy, bias, gsrc, M, N, K, ep);
  };
  auto spmm = [&](const int* rp, const int* col, const float* val, const unsigned short* xb,
                  const float* residF, const unsigned short* residB,
                  const unsigned short* residB2, float beta,
                  float* y, unsigned short* yb, float* sum, unsigned short* sumbf,
                  float alpha, int nrows){
    spmm_bf_kernel<<<(nrows+3)/4, 256, 0, stream>>>(rp, col, val, xb, residF, residB, residB2, beta,
                                                    y, yb, sum, sumbf, alpha, nrows);
  };

  // ---- CSR build ----
  hipMemsetAsync(xp + p_cnt_sim, 0, p_cnt_end - p_cnt_sim, stream);
  hist_all_kernel<<<2048, 256, 0, stream>>>(sim_src, cnt_sim, hg_q, cnt_hgq, hg_c, cnt_hgc, gcn_dst, cnt_gcn);
  scan_local_all_kernel<<<200, 1024, 0, stream>>>(cnt_sim, rp_sim, cnt_hgq, rp_hgq,
                                                  cnt_hgc, rp_hgc, cnt_gcn, rp_gcn, bsum, dinv);
  scan_bsum_all_kernel<<<4, 128, 0, stream>>>(bsum);
  scan_add_all_kernel<<<798, 256, 0, stream>>>(rp_sim, cnt_sim, rp_hgq, cnt_hgq,
                                               rp_hgc, cnt_hgc, rp_gcn, cnt_gcn, bsum);
  scatter_all_kernel<<<2048, 256, 0, stream>>>(
      sim_src, sim_dst, sim_vals, cnt_sim, col_sim, val_sim,
      hg_q, hg_c, hg_vals_qc, hg_vals_cq,
      cnt_hgq, col_hgq, val_hgq, cnt_hgc, col_hgc, val_hgc,
      gcn_dst, gcn_src, cnt_gcn, src_gcn);

  // ---- weight converts ----
  cvt_bf16_kernel<<<2048, 256, 0, stream>>>(q_emb, q_emb_bf, (long)(NQc+1)*Dc);
  cvt_weights_kernel<<<1154, 256, 0, stream>>>(w_ih, w_ih_bf, fc1_w, fc1_wT, w_g3, w_g3T,
                                               w_hh, w_hh_h, b_ih, b_hh, biasP);

  // ---- channel 3 (bf16-only intermediates): e0=three_gate -> bfY; e1 -> bfX; three_sum -> bfZ ----
  {
    dim3 g(1, (NQc+127)/128);
    mfma_gemm_kernel<<<g, 256, 0, stream>>>(q_emb_bf, Dc, q_emb_bf, Dc, Dc, w_g3T,
                                            nullptr, bfY, b_g3, nullptr, q_emb,
                                            nullptr, nullptr, nullptr, NQc, Dc, Dc, 1);
  }
  spmm(rp_sim, col_sim, val_sim, bfY, nullptr, bfY, nullptr, 0.f,
       nullptr, bfX, nullptr, nullptr, 1.f, NQc);                       // e1 = S@e0 + e0
  spmm(rp_sim, col_sim, val_sim, bfX, nullptr, bfY, bfX, 2.f,
       nullptr, bfZ, nullptr, nullptr, 1.f, NQc);                       // three_sum = S@e1 + e0 + 2*e1

  // ---- gated skill embeddings ----
  gemm32(s_emb, Dc, w_g1, one_gate, og_bf, ssum, b_g1, s_emb, NSc, Dc, Dc, 1);
  gemm32(s_emb, Dc, w_g2, two_gate, nullptr, nullptr, b_g2, s_emb, NSc, Dc, Dc, 1);

  // ---- channel 1: hypergraph 2-hop (bfY reused for m1/m2; one_q -> bfX) ----
  spmm(rp_hgq, col_hgq, val_hgq, og_bf,  nullptr, nullptr, nullptr, 0.f,
       nullptr, bfY, nullptr, nullptr, 1.f, NQc);                       // m1
  spmm(rp_hgc, col_hgc, val_hgc, bfY,    one_gate, nullptr, nullptr, 0.f,
       sxB, sxB_bf, ssum, nullptr, 1.f, NSc);                           // e1
  spmm(rp_hgq, col_hgq, val_hgq, sxB_bf, nullptr, nullptr, nullptr, 0.f,
       nullptr, bfY, nullptr, nullptr, 1.f, NQc);                       // m2
  spmm(rp_hgc, col_hgc, val_hgc, bfY,    sxB, nullptr, nullptr, 0.f,
       nullptr, nullptr, ssum, ssum_bf, 1.f, NSc);                      // e2 (-> ssum, ssum_bf)
  spmm(rp_hgq, col_hgq, val_hgq, ssum_bf, nullptr, nullptr, nullptr, 0.f,
       nullptr, bfX, nullptr, nullptr, 1.f/3.f, NQc);                   // one_q

  // ---- channel 2: 3-layer GCN -> gxA ----
  gemm32(two_gate, Dc, gcn_w1, htmp, nullptr, nullptr, nullptr, nullptr, NSc, Dc, Dc, 0);
  gcn_spmm_kernel<<<(NSc+3)/4, 256, 0, stream>>>(rp_gcn, src_gcn, dinv, htmp, gcn_b1, gxA, NSc);
  gemm32(gxA, Dc, gcn_w2, htmp, nullptr, nullptr, nullptr, nullptr, NSc, Dc, Dc, 0);
  gcn_spmm_kernel<<<(NSc+3)/4, 256, 0, stream>>>(rp_gcn, src_gcn, dinv, htmp, gcn_b2, gxB, NSc);
  gemm32(gxB, Dc, gcn_w3, htmp, nullptr, nullptr, nullptr, nullptr, NSc, Dc, Dc, 0);
  gcn_spmm_kernel<<<(NSc+3)/4, 256, 0, stream>>>(rp_gcn, src_gcn, dinv, htmp, gcn_b3, gxA, NSc);

  // ---- gather + gated fusion -> lstm_in_bf ----
  gather_fuse_kernel<<<(BTc+3)/4, 256, 0, stream>>>(
      question_seq, skill_seq, answer_seq,
      ssum, bfX, gxA, bfZ,
      s_emb, q_emb, c_emb,
      w_sg1, w_sg2, w_qg1, w_qg3, b_sg1, b_sg2, b_qg1, b_qg3,
      lstm_in_bf);

  // ---- xpart = lstm_in @ w_ihP^T + biasP (MFMA; clobbers phase-A region) ----
  {
    dim3 g(G4c/128, BTc/128);
    mfma_gemm_kernel<<<g, 256, 0, stream>>>(lstm_in_bf, LINc, lstm_in_bf, LINc, LINc, w_ih_bf,
                                            xpart, nullptr, biasP, nullptr, nullptr,
                                            nullptr, nullptr, nullptr, BTc, G4c, LINc, 0);
  }

  // ---- LSTM ----
  lstm_kernel<<<Bc, 512, 0, stream>>>(xpart, w_hh_h, hs_bf);

  // ---- head: fc1+fc2 fused (MFMA ep=3) -> d_out ----
  {
    dim3 g(1, BTc/128);
    mfma_gemm_kernel<<<g, 256, 0, stream>>>(hs_bf, HTc, lstm_in_bf, LINc, HTc, fc1_wT,
                                            nullptr, nullptr, fc1_b, nullptr, nullptr,
                                            fc2_w, fc2_b, outp, BTc, 128, 384, 3);
  }
}